// Round 7
// baseline (513.893 us; speedup 1.0000x reference)
//
#include <hip/hip_runtime.h>
#include <math.h>

#define D_MODELC 128
#define NSAMP 8
#define DFF 512
#define NCROSS 3
#define NSELF 2
#define BB 2
#define NCAM 5
#define QQ 2500
#define HFI 24
#define WFI 77
#define VXC 32
#define VYC 16
#define VZC 32
#define BQ (BB*QQ)
#define HWI (HFI*WFI)
#define NVOX (VYC*VXC*VZC)

typedef float f4 __attribute__((ext_vector_type(4)));
typedef short s8v __attribute__((ext_vector_type(8)));

__device__ __forceinline__ unsigned short f2bf(float f) {
  union { float f; unsigned u; } v; v.f = f;
  unsigned r = v.u + 0x7FFFu + ((v.u >> 16) & 1u);
  return (unsigned short)(r >> 16);
}
__device__ __forceinline__ float bf2f(unsigned short u) {
  union { unsigned u; float f; } v; v.u = ((unsigned)u) << 16; return v.f;
}

__device__ __forceinline__ bool mask_at(const unsigned char* m, int fl, int idx) {
  if (fl) return m[idx] != 0;
  return ((const int*)m)[idx] != 0;
}

// ---------------- mask detect + per-(b,q) stats (one block) ----------------
__global__ __launch_bounds__(1024) void mask_k(const unsigned char* __restrict__ m,
                                               int* __restrict__ flag,
                                               float* __restrict__ invden, float* __restrict__ imc,
                                               float* __restrict__ many) {
  __shared__ int f;
  if (threadIdx.x == 0) f = 0;
  __syncthreads();
  const int total = BB * NCAM * QQ;
  int loc = 0;
  for (int i = threadIdx.x; i < total; i += 1024)
    if ((i & 3) && m[i]) loc = 1;
  if (loc) atomicOr(&f, 1);
  __syncthreads();
  int fl = f;
  if (threadIdx.x == 0) *flag = fl;
  for (int i = threadIdx.x; i < BQ; i += 1024) {
    int b = i / QQ, q = i % QQ;
    float cnt = 0.f;
    for (int n = 0; n < NCAM; ++n)
      cnt += mask_at(m, fl, (b * NCAM + n) * QQ + q) ? 1.f : 0.f;
    float inv = 1.f / (cnt + 1e-6f);
    invden[i] = inv;
    imc[i] = cnt * inv;
    many[i] = cnt > 0.f ? 1.f : 0.f;
  }
}

// ---------------- image transpose [BN,C,H,W] f32 -> [BN,H,W,C] bf16 ----------------
__global__ __launch_bounds__(256) void transpose_img_k(const float* __restrict__ in,
                                                       unsigned short* __restrict__ out) {
  __shared__ float til[32][65];
  int bn = blockIdx.z;
  int c0 = blockIdx.y * 32;
  int yx0 = blockIdx.x * 64;
  int t = threadIdx.x;
  {
    int yx_l = t & 63, c_l = t >> 6;
    int yx = yx0 + yx_l;
#pragma unroll
    for (int i = 0; i < 8; ++i) {
      int c = c_l + 4 * i;
      float v = 0.f;
      if (yx < HWI) v = in[((size_t)(bn * D_MODELC + c0 + c)) * HWI + yx];
      til[c][yx_l] = v;
    }
  }
  __syncthreads();
  {
    int yx_l = t >> 2, cc = (t & 3) * 8;
    int yx = yx0 + yx_l;
    if (yx < HWI) {
      union { unsigned short u[8]; s8v v; } pk;
#pragma unroll
      for (int j = 0; j < 8; ++j) pk.u[j] = f2bf(til[cc + j][yx_l]);
      *(s8v*)(out + ((size_t)bn * HWI + yx) * D_MODELC + c0 + cc) = pk.v;
    }
  }
}

// ---------------- vol zero + winner init ----------------
__global__ __launch_bounds__(256) void zero_vol_k(unsigned short* __restrict__ vol,
                                                  int* __restrict__ winner) {
  int idx = blockIdx.x * 256 + threadIdx.x;
  const int nv16 = (BB * NVOX * 128) / 8;
  if (idx < nv16) {
    uint4 z = make_uint4(0, 0, 0, 0);
    *(uint4*)(vol + (size_t)idx * 8) = z;
  }
  const int nw4 = (BB * NVOX) / 4;
  if (idx < nw4) {
    int4 m = make_int4(-1, -1, -1, -1);
    *(int4*)(winner + (size_t)idx * 4) = m;
  }
}

__global__ void scatter_winner_k(const int* __restrict__ xi, const int* __restrict__ yi,
                                 const int* __restrict__ zi, int* __restrict__ winner) {
  int i = blockIdx.x * blockDim.x + threadIdx.x;
  if (i >= BQ) return;
  int b = i / QQ;
  int vox = yi[i] * (VXC * VZC) + xi[i] * VZC + zi[i];
  atomicMax(&winner[b * NVOX + vox], i % QQ);
}

__global__ void scatter_write_k(const int* __restrict__ xi, const int* __restrict__ yi,
                                const int* __restrict__ zi, const int* __restrict__ winner,
                                const float* __restrict__ qb, unsigned short* __restrict__ vol) {
  int idx = blockIdx.x * blockDim.x + threadIdx.x;
  if (idx >= BQ * 16) return;
  int g = idx & 15, row = idx >> 4;
  int b = row / QQ, q = row % QQ;
  int vox = yi[row] * (VXC * VZC) + xi[row] * VZC + zi[row];
  if (winner[b * NVOX + vox] != q) return;
  const float* src = qb + (size_t)row * 128 + g * 8;
  float4 a = *(const float4*)src;
  float4 c = *(const float4*)(src + 4);
  union { unsigned short u[8]; s8v v; } pk;
  pk.u[0] = f2bf(a.x); pk.u[1] = f2bf(a.y); pk.u[2] = f2bf(a.z); pk.u[3] = f2bf(a.w);
  pk.u[4] = f2bf(c.x); pk.u[5] = f2bf(c.y); pk.u[6] = f2bf(c.z); pk.u[7] = f2bf(c.w);
  *(s8v*)(vol + ((size_t)b * NVOX + vox) * 128 + g * 8) = pk.v;
}

// ---------------- setup: Qbuf = w_w@op_w (z<5) + f1T/f2T bf16 transpose (z>=5) ----------------
__global__ __launch_bounds__(256) void tpre_k(const float* __restrict__ c_w_w, const float* __restrict__ s_w_w,
                                              const float* __restrict__ c_op_w, const float* __restrict__ s_op_w,
                                              const float* __restrict__ cf1, const float* __restrict__ sf1,
                                              const float* __restrict__ cf2, const float* __restrict__ sf2,
                                              float* __restrict__ Qbuf,
                                              unsigned short* __restrict__ f1T, unsigned short* __restrict__ f2T) {
  __shared__ float As_[32][64];
  __shared__ float Ws_[32][64];
  int z = blockIdx.z, tid = threadIdx.x;
  if (z < 5) {
    const float* A = (z < 3) ? c_w_w + (size_t)z * 16384 : s_w_w + (size_t)(z - 3) * 16384;
    const float* Bm = (z < 3) ? c_op_w + (size_t)z * 16384 : s_op_w + (size_t)(z - 3) * 16384;
    float* C = Qbuf + (size_t)z * 16384;
    int m0 = blockIdx.x * 64, n0 = blockIdx.y * 64;
    float acc[4][4] = {};
    int mr = (tid >> 4) * 4, nc = (tid & 15) * 4;
    for (int k0 = 0; k0 < 128; k0 += 32) {
      {
        int r = tid >> 2, kq = (tid & 3) * 8;
        const float* ap = A + (size_t)(m0 + r) * 128 + k0 + kq;
        float4 v0 = *(const float4*)ap, v1 = *(const float4*)(ap + 4);
        As_[kq + 0][r] = v0.x; As_[kq + 1][r] = v0.y; As_[kq + 2][r] = v0.z; As_[kq + 3][r] = v0.w;
        As_[kq + 4][r] = v1.x; As_[kq + 5][r] = v1.y; As_[kq + 6][r] = v1.z; As_[kq + 7][r] = v1.w;
      }
      {
        int kr = tid >> 3, nq = (tid & 7) * 8;
        const float* wp = Bm + (size_t)(k0 + kr) * 128 + n0 + nq;
        *(float4*)&Ws_[kr][nq] = *(const float4*)wp;
        *(float4*)&Ws_[kr][nq + 4] = *(const float4*)(wp + 4);
      }
      __syncthreads();
#pragma unroll
      for (int kk = 0; kk < 32; ++kk) {
        float4 av = *(const float4*)&As_[kk][mr];
        float4 bv = *(const float4*)&Ws_[kk][nc];
        float a_[4] = {av.x, av.y, av.z, av.w};
        float b_[4] = {bv.x, bv.y, bv.z, bv.w};
#pragma unroll
        for (int i = 0; i < 4; ++i)
#pragma unroll
          for (int j = 0; j < 4; ++j) acc[i][j] += a_[i] * b_[j];
      }
      __syncthreads();
    }
#pragma unroll
    for (int i = 0; i < 4; ++i) {
      float4 r;
      r.x = acc[i][0]; r.y = acc[i][1]; r.z = acc[i][2]; r.w = acc[i][3];
      *(float4*)(C + (size_t)(m0 + mr + i) * 128 + n0 + nc) = r;
    }
  } else {
    int bid = (z - 5) * 4 + blockIdx.y * 2 + blockIdx.x;
    int widx = bid >> 6, chunk = bid & 63;
    const float* src; unsigned short* dst; int K, N;
    if (widx < 5) {
      src = (widx < 3) ? cf1 + (size_t)widx * 65536 : sf1 + (size_t)(widx - 3) * 65536;
      dst = f1T + (size_t)widx * 65536; K = 128; N = 512;
    } else {
      int L = widx - 5;
      src = (L < 3) ? cf2 + (size_t)L * 65536 : sf2 + (size_t)(L - 3) * 65536;
      dst = f2T + (size_t)L * 65536; K = 512; N = 128;
    }
    int e = (chunk * 256 + tid) * 4;
    int k = e % K, n = e / K;
    ushort4 o;
    o.x = f2bf(src[(size_t)(k + 0) * N + n]);
    o.y = f2bf(src[(size_t)(k + 1) * N + n]);
    o.z = f2bf(src[(size_t)(k + 2) * N + n]);
    o.w = f2bf(src[(size_t)(k + 3) * N + n]);
    *(ushort4*)(dst + e) = o;
  }
}

// ---------------- setup: Wcbuf = vp_w @ Qbuf ----------------
struct P5 { const float* a[5]; const float* b[5]; float* c[5]; };

__global__ __launch_bounds__(256) void small_mm_k(P5 ps) {
  const float* A = ps.a[blockIdx.z];
  const float* Bm = ps.b[blockIdx.z];
  float* C = ps.c[blockIdx.z];
  __shared__ float As_[32][64];
  __shared__ float Ws_[32][64];
  int m0 = blockIdx.x * 64, n0 = blockIdx.y * 64, tid = threadIdx.x;
  float acc[4][4] = {};
  int mr = (tid >> 4) * 4, nc = (tid & 15) * 4;
  for (int k0 = 0; k0 < 128; k0 += 32) {
    {
      int r = tid >> 2, kq = (tid & 3) * 8;
      const float* ap = A + (size_t)(m0 + r) * 128 + k0 + kq;
      float4 v0 = *(const float4*)ap, v1 = *(const float4*)(ap + 4);
      As_[kq + 0][r] = v0.x; As_[kq + 1][r] = v0.y; As_[kq + 2][r] = v0.z; As_[kq + 3][r] = v0.w;
      As_[kq + 4][r] = v1.x; As_[kq + 5][r] = v1.y; As_[kq + 6][r] = v1.z; As_[kq + 7][r] = v1.w;
    }
    {
      int kr = tid >> 3, nq = (tid & 7) * 8;
      const float* wp = Bm + (size_t)(k0 + kr) * 128 + n0 + nq;
      *(float4*)&Ws_[kr][nq] = *(const float4*)wp;
      *(float4*)&Ws_[kr][nq + 4] = *(const float4*)(wp + 4);
    }
    __syncthreads();
#pragma unroll
    for (int kk = 0; kk < 32; ++kk) {
      float4 av = *(const float4*)&As_[kk][mr];
      float4 bv = *(const float4*)&Ws_[kk][nc];
      float a_[4] = {av.x, av.y, av.z, av.w};
      float b_[4] = {bv.x, bv.y, bv.z, bv.w};
#pragma unroll
      for (int i = 0; i < 4; ++i)
#pragma unroll
        for (int j = 0; j < 4; ++j) acc[i][j] += a_[i] * b_[j];
    }
    __syncthreads();
  }
#pragma unroll
  for (int i = 0; i < 4; ++i) {
    float4 r;
    r.x = acc[i][0]; r.y = acc[i][1]; r.z = acc[i][2]; r.w = acc[i][3];
    *(float4*)(C + (size_t)(m0 + mr + i) * 128 + n0 + nc) = r;
  }
}

// ---------------- setup: WcT conv (y<5) + pre_vec (y==5) ----------------
__global__ __launch_bounds__(256) void wpre_k(const float* __restrict__ Wcbuf,
                                              unsigned short* __restrict__ WcT,
                                              const float* __restrict__ c_vp_b, const float* __restrict__ c_w_b,
                                              const float* __restrict__ s_vp_b, const float* __restrict__ s_w_b,
                                              const float* __restrict__ c_op_w, const float* __restrict__ s_op_w,
                                              const float* __restrict__ Qbuf,
                                              float* __restrict__ v1buf, float* __restrict__ v2buf,
                                              float* __restrict__ csbuf) {
  int t = threadIdx.x;
  if (blockIdx.y < 5) {
    int L = blockIdx.y;
    const float* src = Wcbuf + (size_t)L * 16384;
    unsigned short* dst = WcT + (size_t)L * 16384;
    int e = (blockIdx.x * 256 + t) * 4;
    int k = e & 127, n = e >> 7;
    ushort4 o;
    o.x = f2bf(src[(size_t)(k + 0) * 128 + n]);
    o.y = f2bf(src[(size_t)(k + 1) * 128 + n]);
    o.z = f2bf(src[(size_t)(k + 2) * 128 + n]);
    o.w = f2bf(src[(size_t)(k + 3) * 128 + n]);
    *(ushort4*)(dst + e) = o;
  } else if (blockIdx.x < 5 && t < 128) {
    int L = blockIdx.x, n = t;
    const float* vpb = L < 3 ? c_vp_b + L * 128 : s_vp_b + (L - 3) * 128;
    const float* wb = L < 3 ? c_w_b + L * 128 : s_w_b + (L - 3) * 128;
    const float* op = L < 3 ? c_op_w + (size_t)L * 16384 : s_op_w + (size_t)(L - 3) * 16384;
    const float* Q = Qbuf + (size_t)L * 16384;
    float a = 0.f, c = 0.f;
    for (int k = 0; k < 128; ++k) {
      a += vpb[k] * Q[k * 128 + n];
      c += wb[k] * op[k * 128 + n];
    }
    if (L < 3) { v1buf[L * 128 + n] = a; v2buf[L * 128 + n] = c; }
    else csbuf[(L - 3) * 128 + n] = a + c;
  }
}

// ================= CROSS MEGA: 3 layers fused, 8 rows/block, 512 thr, 625 blocks =================
__global__ __launch_bounds__(512) void cross_mega_k(
    const float* __restrict__ query, const float* __restrict__ refp,
    const unsigned char* __restrict__ maskp, const int* __restrict__ flagp,
    const float* __restrict__ invden, const float* __restrict__ imc,
    const unsigned short* __restrict__ imgT,
    const float* __restrict__ ln1g, const float* __restrict__ ln1b,
    const float* __restrict__ dpw_, const float* __restrict__ dpb_,
    const float* __restrict__ aw_, const float* __restrict__ ab_,
    const unsigned short* __restrict__ WcT, const float* __restrict__ opb_,
    const float* __restrict__ v1_, const float* __restrict__ v2_,
    const float* __restrict__ ln2g, const float* __restrict__ ln2b,
    const unsigned short* __restrict__ f1T, const float* __restrict__ b1_,
    const unsigned short* __restrict__ f2T, const float* __restrict__ b2_,
    float* __restrict__ qb) {
  __shared__ float qtile[8][136];
  __shared__ float pr[8][24];
  __shared__ float awa[8];
  __shared__ __align__(16) unsigned short As[16 * 128];
  // scratch must hold Hs = 16 rows x 512 cols x 2B = 16384 B (rows 8-15 are
  // MFMA zero-padding, rewritten every layer since soff/sw alias rows 0-10).
  __shared__ __align__(16) char scratch[16896];
  int* soff = (int*)scratch;                        // [320][4]
  float* sw = (float*)(scratch + 5120);             // [320][4]
  float* wl = (float*)scratch;                      // [24][132]
  unsigned short* Hs = (unsigned short*)scratch;    // [16][512]

  int t = threadIdx.x;
  int m0 = blockIdx.x * 8;
  int wv = t >> 6, lane = t & 63;
  int la = lane & 15, lb = lane >> 4;
  int fl = *flagp;
  // init qtile + zero As rows 8-15
  if (lane < 32)
    *(float4*)&qtile[wv][lane * 4] = *(const float4*)(query + (size_t)(m0 + wv) * 128 + lane * 4);
  if (t < 128) {
    s8v z = {};
    *(s8v*)&As[(8 + (t >> 4)) * 128 + (t & 15) * 8] = z;
  }
  __syncthreads();

  for (int L = 0; L < NCROSS; ++L) {
    const float* dpw = dpw_ + (size_t)L * 2048;
    const float* dpb = dpb_ + L * 16;
    const float* aw = aw_ + (size_t)L * 1024;
    const float* ab = ab_ + L * 8;
    const float* g1 = ln1g + L * 128;
    const float* be1 = ln1b + L * 128;
    // A1: stage proj weights [24][132]
    for (int idx = t; idx < 24 * 128; idx += 512) {
      int c = idx >> 7, k = idx & 127;
      wl[c * 132 + k] = (c < 16) ? dpw[k * 16 + c] : aw[k * 8 + (c - 16)];
    }
    __syncthreads();
    // A2: LN + proj (wave per row)
    {
      int c0 = lane * 2;
      float x0 = qtile[wv][c0], x1 = qtile[wv][c0 + 1];
      float s1 = x0 + x1, s2 = x0 * x0 + x1 * x1;
#pragma unroll
      for (int msk = 1; msk < 64; msk <<= 1) { s1 += __shfl_xor(s1, msk); s2 += __shfl_xor(s2, msk); }
      float mean = s1 * (1.f / 128.f);
      float var = s2 * (1.f / 128.f) - mean * mean;
      float inv = rsqrtf(var + 1e-5f);
      float l0 = (x0 - mean) * inv * g1[c0] + be1[c0];
      float l1 = (x1 - mean) * inv * g1[c0 + 1] + be1[c0 + 1];
      float p[24];
#pragma unroll
      for (int c = 0; c < 24; ++c)
        p[c] = l0 * wl[c * 132 + c0] + l1 * wl[c * 132 + c0 + 1];
#pragma unroll
      for (int msk = 1; msk < 64; msk <<= 1) {
#pragma unroll
        for (int c = 0; c < 24; ++c) p[c] += __shfl_xor(p[c], msk);
      }
      if (lane == 0) {
#pragma unroll
        for (int c = 0; c < 24; ++c) pr[wv][c] = p[c];
      }
    }
    __syncthreads();
    // B1: per-entry offsets/weights + inline softmax
    if (t < 320) {
      int qi = t / 40, rem = t % 40;
      int n = rem >> 3, s = rem & 7;
      int row = m0 + qi;
      int b = row / QQ, q = row - b * QQ;
      int mi = (b * NCAM + n) * QQ + q;
      bool mk = mask_at(maskp, fl, mi);
      float mx = -1e30f;
      float av[8];
#pragma unroll
      for (int i = 0; i < 8; ++i) { av[i] = pr[qi][16 + i] + ab[i]; mx = fmaxf(mx, av[i]); }
      float sm = 0.f, es = 0.f;
#pragma unroll
      for (int i = 0; i < 8; ++i) {
        float e_ = expf(av[i] - mx);
        sm += e_;
        if (i == s) es = e_;
      }
      float a = mk ? es / sm : 0.f;
      float rx = refp[(size_t)mi * 2 + 0];
      float ry = refp[(size_t)mi * 2 + 1];
      float fx = (rx + pr[qi][s * 2 + 0] + dpb[s * 2 + 0]) * (float)(WFI - 1);
      float fy = (ry + pr[qi][s * 2 + 1] + dpb[s * 2 + 1]) * (float)(HFI - 1);
      float x0f = floorf(fx), y0f = floorf(fy);
      int x0 = (int)x0f, y0 = (int)y0f;
      float xd = fx - x0f, yd = fy - y0f;
      int base = (b * NCAM + n) * HWI;
#pragma unroll
      for (int cy = 0; cy < 2; ++cy)
#pragma unroll
        for (int cx = 0; cx < 2; ++cx) {
          int xi = x0 + cx, yi = y0 + cy;
          bool ok = (xi >= 0) & (xi < WFI) & (yi >= 0) & (yi < HFI);
          int xc = min(max(xi, 0), WFI - 1), yc = min(max(yi, 0), HFI - 1);
          soff[t * 4 + cy * 2 + cx] = (base + yc * WFI + xc) * 128;
          sw[t * 4 + cy * 2 + cx] = ok ? a * (cx ? xd : 1.f - xd) * (cy ? yd : 1.f - yd) : 0.f;
        }
    }
    __syncthreads();
    // B2: gather, wave per query, 4 entry-groups x 16 ch-groups, branch-free
    {
      int qi = wv, ln = lane & 15, eg = lane >> 4;
      float acc[8] = {};
      float wa = 0.f;
      for (int e = eg * 10; e < eg * 10 + 10; ++e) {
        int eb = qi * 40 + e;
        float4 wv4 = *(const float4*)&sw[eb * 4];
        int4 ov = *(const int4*)&soff[eb * 4];
        s8v p0 = *(const s8v*)(imgT + (size_t)ov.x + ln * 8);
        s8v p1 = *(const s8v*)(imgT + (size_t)ov.y + ln * 8);
        s8v p2 = *(const s8v*)(imgT + (size_t)ov.z + ln * 8);
        s8v p3 = *(const s8v*)(imgT + (size_t)ov.w + ln * 8);
#pragma unroll
        for (int i = 0; i < 8; ++i)
          acc[i] += wv4.x * bf2f((unsigned short)p0[i]) + wv4.y * bf2f((unsigned short)p1[i])
                  + wv4.z * bf2f((unsigned short)p2[i]) + wv4.w * bf2f((unsigned short)p3[i]);
        wa += wv4.x + wv4.y + wv4.z + wv4.w;
      }
#pragma unroll
      for (int i = 0; i < 8; ++i) { acc[i] += __shfl_xor(acc[i], 16); acc[i] += __shfl_xor(acc[i], 32); }
      wa += __shfl_xor(wa, 16); wa += __shfl_xor(wa, 32);
      if (eg == 0) {
        union { unsigned short u[8]; s8v v; } pk;
#pragma unroll
        for (int i = 0; i < 8; ++i) pk.u[i] = f2bf(acc[i]);
        *(s8v*)&As[qi * 128 + ((ln ^ (qi & 7)) << 3)] = pk.v;
        if (ln == 0) awa[qi] = wa;
      }
    }
    __syncthreads();
    // B3: op-GEMM (M=16 padded) + epilogue -> qtile
    {
      const unsigned short* Wc = WcT + (size_t)L * 16384;
      const float* v1L = v1_ + L * 128;
      const float* v2L = v2_ + L * 128;
      const float* opbL = opb_ + L * 128;
      f4 accm = {};
      int col = wv * 16 + la;
#pragma unroll
      for (int ks = 0; ks < 4; ++ks) {
        s8v af = *(const s8v*)&As[la * 128 + (((ks * 4 + lb) ^ (la & 7)) << 3)];
        s8v bf = *(const s8v*)(Wc + (size_t)col * 128 + ks * 32 + lb * 8);
        accm = __builtin_amdgcn_mfma_f32_16x16x32_bf16(af, bf, accm, 0, 0, 0);
      }
#pragma unroll
      for (int j = 0; j < 4; ++j) {
        int lr = lb * 4 + j;
        if (lr < 8) {
          int m = m0 + lr;
          float s0m = invden[m];
          qtile[lr][col] += accm[j] * s0m + s0m * awa[lr] * v1L[col] + imc[m] * v2L[col] + opbL[col];
        }
      }
    }
    __syncthreads();
    // C1: LN2 -> As (bf16, swizzled)
    {
      const float* g2 = ln2g + L * 128;
      const float* be2 = ln2b + L * 128;
      int c0 = lane * 2;
      float x0 = qtile[wv][c0], x1 = qtile[wv][c0 + 1];
      float s1 = x0 + x1, s2 = x0 * x0 + x1 * x1;
#pragma unroll
      for (int msk = 1; msk < 64; msk <<= 1) { s1 += __shfl_xor(s1, msk); s2 += __shfl_xor(s2, msk); }
      float mean = s1 * (1.f / 128.f);
      float var = s2 * (1.f / 128.f) - mean * mean;
      float inv = rsqrtf(var + 1e-5f);
      unsigned u0 = f2bf((x0 - mean) * inv * g2[c0] + be2[c0]);
      unsigned u1 = f2bf((x1 - mean) * inv * g2[c0 + 1] + be2[c0 + 1]);
      int chunk = lane >> 2, idx2 = (lane & 3) * 2;
      *(unsigned*)&As[wv * 128 + ((chunk ^ (wv & 7)) << 3) + idx2] = u0 | (u1 << 16);
    }
    __syncthreads();
    // C2: ff1 + GELU -> Hs (rows 8-15 zero-filled each layer)
    {
      const unsigned short* W1 = f1T + (size_t)L * 65536;
      const float* b1 = b1_ + L * 512;
      f4 acc1[4] = {};
#pragma unroll
      for (int ks = 0; ks < 4; ++ks) {
        s8v af = *(const s8v*)&As[la * 128 + (((ks * 4 + lb) ^ (la & 7)) << 3)];
#pragma unroll
        for (int ti = 0; ti < 4; ++ti) {
          int col = (wv * 4 + ti) * 16 + la;
          s8v bf = *(const s8v*)(W1 + (size_t)col * 128 + ks * 32 + lb * 8);
          acc1[ti] = __builtin_amdgcn_mfma_f32_16x16x32_bf16(af, bf, acc1[ti], 0, 0, 0);
        }
      }
#pragma unroll
      for (int ti = 0; ti < 4; ++ti) {
        int col = (wv * 4 + ti) * 16 + la;
        int chunk = col >> 3, idx = col & 7;
#pragma unroll
        for (int j = 0; j < 4; ++j) {
          int m = lb * 4 + j;
          float val = 0.f;
          if (m < 8) {
            val = acc1[ti][j] + b1[col];
            val = 0.5f * val * (1.f + erff(val * 0.70710678118654752f));
          }
          Hs[m * 512 + ((chunk ^ (m & 7)) << 3) + idx] = f2bf(val);
        }
      }
    }
    __syncthreads();
    // C3: ff2 + residual -> qtile
    {
      const unsigned short* W2 = f2T + (size_t)L * 65536;
      const float* b2 = b2_ + L * 128;
      f4 acc2 = {};
      int col = wv * 16 + la;
#pragma unroll
      for (int ks = 0; ks < 16; ++ks) {
        s8v af = *(const s8v*)&Hs[la * 512 + (((ks * 4 + lb) ^ (la & 7)) << 3)];
        s8v bf = *(const s8v*)(W2 + (size_t)col * 512 + ks * 32 + lb * 8);
        acc2 = __builtin_amdgcn_mfma_f32_16x16x32_bf16(af, bf, acc2, 0, 0, 0);
      }
#pragma unroll
      for (int j = 0; j < 4; ++j) {
        int lr = lb * 4 + j;
        if (lr < 8) qtile[lr][col] += acc2[j] + b2[col];
      }
    }
    __syncthreads();
  }
  if (lane < 32)
    *(float4*)(qb + (size_t)(m0 + wv) * 128 + lane * 4) = *(const float4*)&qtile[wv][lane * 4];
}

// ================= SELF MEGA: 1 layer, 8 rows/block, 512 thr, optional classifier =================
template <bool CLS>
__global__ __launch_bounds__(512) void self_mega_k(
    const float* __restrict__ qbin, const float* __restrict__ ref3d,
    const unsigned short* __restrict__ vol, const float* __restrict__ many,
    const float* __restrict__ ln1g, const float* __restrict__ ln1b,
    const float* __restrict__ dpw, const float* __restrict__ dpb,
    const float* __restrict__ aw, const float* __restrict__ ab,
    const unsigned short* __restrict__ WcT, const float* __restrict__ opb,
    const float* __restrict__ csb,
    const float* __restrict__ ln2g, const float* __restrict__ ln2b,
    const unsigned short* __restrict__ f1T, const float* __restrict__ b1,
    const unsigned short* __restrict__ f2T, const float* __restrict__ b2,
    float* __restrict__ qb,
    const float* __restrict__ cw, const float* __restrict__ cb, float* __restrict__ out) {
  __shared__ float qtile[8][136];
  __shared__ float pr[8][32];
  __shared__ __align__(16) unsigned short As[16 * 128];
  __shared__ __align__(16) char scratch[16896];
  int* soff = (int*)scratch;                      // [64][8]
  float* sw = (float*)(scratch + 2048);           // [64][8]
  float* wl = (float*)scratch;                    // [32][132]
  unsigned short* Hs = (unsigned short*)scratch;  // [16][512]

  int t = threadIdx.x;
  int m0 = blockIdx.x * 8;
  int wv = t >> 6, lane = t & 63;
  int la = lane & 15, lb = lane >> 4;
  if (lane < 32)
    *(float4*)&qtile[wv][lane * 4] = *(const float4*)(qbin + (size_t)(m0 + wv) * 128 + lane * 4);
  if (t < 128) {
    s8v z = {};
    *(s8v*)&As[(8 + (t >> 4)) * 128 + (t & 15) * 8] = z;
  }
  // A1: stage proj weights [32][132]
  for (int idx = t; idx < 32 * 128; idx += 512) {
    int c = idx >> 7, k = idx & 127;
    wl[c * 132 + k] = (c < 24) ? dpw[k * 24 + c] : aw[k * 8 + (c - 24)];
  }
  __syncthreads();
  // A2: LN + proj
  {
    int c0 = lane * 2;
    float x0 = qtile[wv][c0], x1 = qtile[wv][c0 + 1];
    float s1 = x0 + x1, s2 = x0 * x0 + x1 * x1;
#pragma unroll
    for (int msk = 1; msk < 64; msk <<= 1) { s1 += __shfl_xor(s1, msk); s2 += __shfl_xor(s2, msk); }
    float mean = s1 * (1.f / 128.f);
    float var = s2 * (1.f / 128.f) - mean * mean;
    float inv = rsqrtf(var + 1e-5f);
    float l0 = (x0 - mean) * inv * ln1g[c0] + ln1b[c0];
    float l1 = (x1 - mean) * inv * ln1g[c0 + 1] + ln1b[c0 + 1];
    float p[32];
#pragma unroll
    for (int c = 0; c < 32; ++c)
      p[c] = l0 * wl[c * 132 + c0] + l1 * wl[c * 132 + c0 + 1];
#pragma unroll
    for (int msk = 1; msk < 64; msk <<= 1) {
#pragma unroll
      for (int c = 0; c < 32; ++c) p[c] += __shfl_xor(p[c], msk);
    }
    if (lane == 0) {
#pragma unroll
      for (int c = 0; c < 32; ++c) pr[wv][c] = p[c];
    }
  }
  __syncthreads();
  // B1: per-entry offsets + inline softmax + coords (perm [1,0,2])
  if (t < 64) {
    int qi = t >> 3, s = t & 7;
    int row = m0 + qi;
    int b = row / QQ;
    float mx = -1e30f;
    float av[8];
#pragma unroll
    for (int i = 0; i < 8; ++i) { av[i] = pr[qi][24 + i] + ab[i]; mx = fmaxf(mx, av[i]); }
    float sm = 0.f, es = 0.f;
#pragma unroll
    for (int i = 0; i < 8; ++i) {
      float e_ = expf(av[i] - mx);
      sm += e_;
      if (i == s) es = e_;
    }
    float a = es / sm;
    float g0 = pr[qi][s * 3 + 1] + dpb[s * 3 + 1] + ref3d[row * 3 + 1];
    float g1v = pr[qi][s * 3 + 0] + dpb[s * 3 + 0] + ref3d[row * 3 + 0];
    float g2v = pr[qi][s * 3 + 2] + dpb[s * 3 + 2] + ref3d[row * 3 + 2];
    float fx = (g0 + 1.f) * 0.5f * (float)(VZC - 1);
    float fy = (g1v + 1.f) * 0.5f * (float)(VXC - 1);
    float fz = (g2v + 1.f) * 0.5f * (float)(VYC - 1);
    float x0f = floorf(fx), y0f = floorf(fy), z0f = floorf(fz);
    int x0 = (int)x0f, y0 = (int)y0f, z0 = (int)z0f;
    float xd = fx - x0f, yd = fy - y0f, zd = fz - z0f;
    int base = b * NVOX;
#pragma unroll
    for (int cz = 0; cz < 2; ++cz)
#pragma unroll
      for (int cy = 0; cy < 2; ++cy)
#pragma unroll
        for (int cx = 0; cx < 2; ++cx) {
          int xi = x0 + cx, yi = y0 + cy, zi = z0 + cz;
          bool ok = (xi >= 0) & (xi < VZC) & (yi >= 0) & (yi < VXC) & (zi >= 0) & (zi < VYC);
          int xc = min(max(xi, 0), VZC - 1);
          int yc = min(max(yi, 0), VXC - 1);
          int zc = min(max(zi, 0), VYC - 1);
          int ci = cz * 4 + cy * 2 + cx;
          soff[t * 8 + ci] = (base + (zc * VXC + yc) * VZC + xc) * 128;
          sw[t * 8 + ci] = ok ? a * (cx ? xd : 1.f - xd) * (cy ? yd : 1.f - yd) * (cz ? zd : 1.f - zd) : 0.f;
        }
  }
  __syncthreads();
  // B2: gather, wave per query, 4 entry-groups (2 s each) x 16 ch-groups, branch-free
  {
    int qi = wv, ln = lane & 15, eg = lane >> 4;
    float acc[8] = {};
#pragma unroll
    for (int ss = 0; ss < 2; ++ss) {
      int eb = qi * 8 + eg * 2 + ss;
#pragma unroll
      for (int c = 0; c < 8; ++c) {
        float wgt = sw[eb * 8 + c];
        s8v p = *(const s8v*)(vol + (size_t)soff[eb * 8 + c] + ln * 8);
#pragma unroll
        for (int i = 0; i < 8; ++i) acc[i] += wgt * bf2f((unsigned short)p[i]);
      }
    }
#pragma unroll
    for (int i = 0; i < 8; ++i) { acc[i] += __shfl_xor(acc[i], 16); acc[i] += __shfl_xor(acc[i], 32); }
    if (eg == 0) {
      union { unsigned short u[8]; s8v v; } pk;
#pragma unroll
      for (int i = 0; i < 8; ++i) pk.u[i] = f2bf(acc[i]);
      *(s8v*)&As[qi * 128 + ((ln ^ (qi & 7)) << 3)] = pk.v;
    }
  }
  __syncthreads();
  // B3: op-GEMM + epilogue
  {
    f4 accm = {};
    int col = wv * 16 + la;
#pragma unroll
    for (int ks = 0; ks < 4; ++ks) {
      s8v af = *(const s8v*)&As[la * 128 + (((ks * 4 + lb) ^ (la & 7)) << 3)];
      s8v bf = *(const s8v*)(WcT + (size_t)col * 128 + ks * 32 + lb * 8);
      accm = __builtin_amdgcn_mfma_f32_16x16x32_bf16(af, bf, accm, 0, 0, 0);
    }
#pragma unroll
    for (int j = 0; j < 4; ++j) {
      int lr = lb * 4 + j;
      if (lr < 8) {
        int m = m0 + lr;
        float s0m = many[m];
        qtile[lr][col] += accm[j] * s0m + s0m * csb[col] + opb[col];
      }
    }
  }
  __syncthreads();
  // C1: LN2 -> As
  {
    int c0 = lane * 2;
    float x0 = qtile[wv][c0], x1 = qtile[wv][c0 + 1];
    float s1 = x0 + x1, s2 = x0 * x0 + x1 * x1;
#pragma unroll
    for (int msk = 1; msk < 64; msk <<= 1) { s1 += __shfl_xor(s1, msk); s2 += __shfl_xor(s2, msk); }
    float mean = s1 * (1.f / 128.f);
    float var = s2 * (1.f / 128.f) - mean * mean;
    float inv = rsqrtf(var + 1e-5f);
    unsigned u0 = f2bf((x0 - mean) * inv * ln2g[c0] + ln2b[c0]);
    unsigned u1 = f2bf((x1 - mean) * inv * ln2g[c0 + 1] + ln2b[c0 + 1]);
    int chunk = lane >> 2, idx2 = (lane & 3) * 2;
    *(unsigned*)&As[wv * 128 + ((chunk ^ (wv & 7)) << 3) + idx2] = u0 | (u1 << 16);
  }
  __syncthreads();
  // C2: ff1 + GELU -> Hs (rows 8-15 zero-filled)
  {
    f4 acc1[4] = {};
#pragma unroll
    for (int ks = 0; ks < 4; ++ks) {
      s8v af = *(const s8v*)&As[la * 128 + (((ks * 4 + lb) ^ (la & 7)) << 3)];
#pragma unroll
      for (int ti = 0; ti < 4; ++ti) {
        int col = (wv * 4 + ti) * 16 + la;
        s8v bf = *(const s8v*)(f1T + (size_t)col * 128 + ks * 32 + lb * 8);
        acc1[ti] = __builtin_amdgcn_mfma_f32_16x16x32_bf16(af, bf, acc1[ti], 0, 0, 0);
      }
    }
#pragma unroll
    for (int ti = 0; ti < 4; ++ti) {
      int col = (wv * 4 + ti) * 16 + la;
      int chunk = col >> 3, idx = col & 7;
#pragma unroll
      for (int j = 0; j < 4; ++j) {
        int m = lb * 4 + j;
        float val = 0.f;
        if (m < 8) {
          val = acc1[ti][j] + b1[col];
          val = 0.5f * val * (1.f + erff(val * 0.70710678118654752f));
        }
        Hs[m * 512 + ((chunk ^ (m & 7)) << 3) + idx] = f2bf(val);
      }
    }
  }
  __syncthreads();
  // C3: ff2 + residual
  {
    f4 acc2 = {};
    int col = wv * 16 + la;
#pragma unroll
    for (int ks = 0; ks < 16; ++ks) {
      s8v af = *(const s8v*)&Hs[la * 512 + (((ks * 4 + lb) ^ (la & 7)) << 3)];
      s8v bf = *(const s8v*)(f2T + (size_t)col * 512 + ks * 32 + lb * 8);
      acc2 = __builtin_amdgcn_mfma_f32_16x16x32_bf16(af, bf, acc2, 0, 0, 0);
    }
#pragma unroll
    for (int j = 0; j < 4; ++j) {
      int lr = lb * 4 + j;
      if (lr < 8) qtile[lr][col] += acc2[j] + b2[col];
    }
  }
  __syncthreads();
  if (CLS) {
    int c0 = lane * 2;
    float q0 = qtile[wv][c0], q1 = qtile[wv][c0 + 1];
    float ps0 = q0 * cw[c0 * 4 + 0] + q1 * cw[(c0 + 1) * 4 + 0];
    float ps1 = q0 * cw[c0 * 4 + 1] + q1 * cw[(c0 + 1) * 4 + 1];
    float ps2 = q0 * cw[c0 * 4 + 2] + q1 * cw[(c0 + 1) * 4 + 2];
    float ps3 = q0 * cw[c0 * 4 + 3] + q1 * cw[(c0 + 1) * 4 + 3];
#pragma unroll
    for (int msk = 1; msk < 64; msk <<= 1) {
      ps0 += __shfl_xor(ps0, msk);
      ps1 += __shfl_xor(ps1, msk);
      ps2 += __shfl_xor(ps2, msk);
      ps3 += __shfl_xor(ps3, msk);
    }
    if (lane < 4) {
      float o = (lane == 0) ? ps0 : (lane == 1) ? ps1 : (lane == 2) ? ps2 : ps3;
      out[(m0 + wv) * 4 + lane] = o + cb[lane];
    }
  } else {
    if (lane < 32)
      *(float4*)(qb + (size_t)(m0 + wv) * 128 + lane * 4) = *(const float4*)&qtile[wv][lane * 4];
  }
}

extern "C" void kernel_launch(void* const* d_in, const int* in_sizes, int n_in,
                              void* d_out, int out_size, void* d_ws, size_t ws_size,
                              hipStream_t stream) {
  (void)in_sizes; (void)n_in; (void)out_size; (void)ws_size;
  const float* query = (const float*)d_in[0];
  const float* ref_points = (const float*)d_in[1];
  const float* ref3d = (const float*)d_in[2];
  const float* imgf = (const float*)d_in[3];
  const unsigned char* maskp = (const unsigned char*)d_in[4];
  const int* x_idx = (const int*)d_in[5];
  const int* y_idx = (const int*)d_in[6];
  const int* z_idx = (const int*)d_in[7];
  const float* c_ln1_g = (const float*)d_in[8];
  const float* c_ln1_b = (const float*)d_in[9];
  const float* c_dp_w = (const float*)d_in[10];
  const float* c_dp_b = (const float*)d_in[11];
  const float* c_a_w = (const float*)d_in[12];
  const float* c_a_b = (const float*)d_in[13];
  const float* c_w_w = (const float*)d_in[14];
  const float* c_w_b = (const float*)d_in[15];
  const float* c_vp_w = (const float*)d_in[16];
  const float* c_vp_b = (const float*)d_in[17];
  const float* c_op_w = (const float*)d_in[18];
  const float* c_op_b = (const float*)d_in[19];
  const float* c_ln2_g = (const float*)d_in[20];
  const float* c_ln2_b = (const float*)d_in[21];
  const float* c_ff1_w = (const float*)d_in[22];
  const float* c_ff1_b = (const float*)d_in[23];
  const float* c_ff2_w = (const float*)d_in[24];
  const float* c_ff2_b = (const float*)d_in[25];
  const float* s_ln1_g = (const float*)d_in[26];
  const float* s_ln1_b = (const float*)d_in[27];
  const float* s_dp_w = (const float*)d_in[28];
  const float* s_dp_b = (const float*)d_in[29];
  const float* s_a_w = (const float*)d_in[30];
  const float* s_a_b = (const float*)d_in[31];
  const float* s_w_w = (const float*)d_in[32];
  const float* s_w_b = (const float*)d_in[33];
  const float* s_vp_w = (const float*)d_in[34];
  const float* s_vp_b = (const float*)d_in[35];
  const float* s_op_w = (const float*)d_in[36];
  const float* s_op_b = (const float*)d_in[37];
  const float* s_ln2_g = (const float*)d_in[38];
  const float* s_ln2_b = (const float*)d_in[39];
  const float* s_ff1_w = (const float*)d_in[40];
  const float* s_ff1_b = (const float*)d_in[41];
  const float* s_ff2_w = (const float*)d_in[42];
  const float* s_ff2_b = (const float*)d_in[43];
  const float* cls_w = (const float*)d_in[44];
  const float* cls_b = (const float*)d_in[45];
  float* out = (float*)d_out;

  char* ws = (char*)d_ws;
  size_t off = 0;
  auto carve = [&](size_t bytes) -> char* {
    char* p = ws + off;
    off += (bytes + 255) & ~(size_t)255;
    return p;
  };
  int* flag = (int*)carve(256);
  float* invden = (float*)carve(BQ * 4);
  float* imc = (float*)carve(BQ * 4);
  float* many = (float*)carve(BQ * 4);
  float* qb = (float*)carve((size_t)BQ * 128 * 4);
  int* winner = (int*)carve((size_t)BB * NVOX * 4);
  float* Qbuf = (float*)carve((size_t)5 * 16384 * 4);
  float* Wcbuf = (float*)carve((size_t)5 * 16384 * 4);
  unsigned short* WcT = (unsigned short*)carve((size_t)5 * 16384 * 2);
  unsigned short* f1T = (unsigned short*)carve((size_t)5 * 65536 * 2);
  unsigned short* f2T = (unsigned short*)carve((size_t)5 * 65536 * 2);
  float* v1buf = (float*)carve(3 * 128 * 4);
  float* v2buf = (float*)carve(3 * 128 * 4);
  float* csbuf = (float*)carve(2 * 128 * 4);
  unsigned short* imgT = (unsigned short*)carve((size_t)BB * NCAM * HWI * 128 * 2);
  unsigned short* vol = (unsigned short*)carve((size_t)BB * NVOX * 128 * 2);

  const int GB8 = BQ / 8;  // 625

  // ---- setup (7 launches) ----
  mask_k<<<1, 1024, 0, stream>>>(maskp, flag, invden, imc, many);
  tpre_k<<<dim3(2, 2, 165), 256, 0, stream>>>(c_w_w, s_w_w, c_op_w, s_op_w,
                                              c_ff1_w, s_ff1_w, c_ff2_w, s_ff2_w,
                                              Qbuf, f1T, f2T);
  {
    P5 pw;
    for (int L = 0; L < 5; ++L) {
      pw.a[L] = (L < 3) ? c_vp_w + (size_t)L * 16384 : s_vp_w + (size_t)(L - 3) * 16384;
      pw.b[L] = Qbuf + (size_t)L * 16384;
      pw.c[L] = Wcbuf + (size_t)L * 16384;
    }
    small_mm_k<<<dim3(2, 2, 5), 256, 0, stream>>>(pw);
  }
  wpre_k<<<dim3(16, 6), 256, 0, stream>>>(Wcbuf, WcT, c_vp_b, c_w_b, s_vp_b, s_w_b,
                                          c_op_w, s_op_w, Qbuf, v1buf, v2buf, csbuf);
  transpose_img_k<<<dim3((HWI + 63) / 64, 4, BB * NCAM), 256, 0, stream>>>(imgf, imgT);
  zero_vol_k<<<1024, 256, 0, stream>>>(vol, winner);
  scatter_winner_k<<<(BQ + 255) / 256, 256, 0, stream>>>(x_idx, y_idx, z_idx, winner);

  // ---- cross stack: ONE kernel, 3 layers ----
  cross_mega_k<<<GB8, 512, 0, stream>>>(query, ref_points, maskp, flag, invden, imc, imgT,
                                        c_ln1_g, c_ln1_b, c_dp_w, c_dp_b, c_a_w, c_a_b,
                                        WcT, c_op_b, v1buf, v2buf, c_ln2_g, c_ln2_b,
                                        f1T, c_ff1_b, f2T, c_ff2_b, qb);

  // ---- self stack ----
  scatter_write_k<<<(BQ * 16 + 255) / 256, 256, 0, stream>>>(x_idx, y_idx, z_idx, winner, qb, vol);
  self_mega_k<false><<<GB8, 512, 0, stream>>>(qb, ref3d, vol, many,
                                              s_ln1_g, s_ln1_b, s_dp_w, s_dp_b, s_a_w, s_a_b,
                                              WcT + (size_t)3 * 16384, s_op_b, csbuf,
                                              s_ln2_g, s_ln2_b,
                                              f1T + (size_t)3 * 65536, s_ff1_b,
                                              f2T + (size_t)3 * 65536, s_ff2_b,
                                              qb, cls_w, cls_b, out);
  scatter_write_k<<<(BQ * 16 + 255) / 256, 256, 0, stream>>>(x_idx, y_idx, z_idx, winner, qb, vol);
  self_mega_k<true><<<GB8, 512, 0, stream>>>(qb, ref3d, vol, many,
                                             s_ln1_g + 128, s_ln1_b + 128,
                                             s_dp_w + (size_t)128 * 24, s_dp_b + 24,
                                             s_a_w + (size_t)128 * 8, s_a_b + 8,
                                             WcT + (size_t)4 * 16384, s_op_b + 128,
                                             csbuf + 128, s_ln2_g + 128, s_ln2_b + 128,
                                             f1T + (size_t)4 * 65536, s_ff1_b + 512,
                                             f2T + (size_t)4 * 65536, s_ff2_b + 128,
                                             qb, cls_w, cls_b, out);
}

// Round 9
// 417.368 us; speedup vs baseline: 1.2313x; 1.2313x over previous
//
#include <hip/hip_runtime.h>
#include <math.h>

#define D_MODELC 128
#define NSAMP 8
#define DFF 512
#define NCROSS 3
#define NSELF 2
#define BB 2
#define NCAM 5
#define QQ 2500
#define HFI 24
#define WFI 77
#define VXC 32
#define VYC 16
#define VZC 32
#define BQ (BB*QQ)
#define HWI (HFI*WFI)
#define NVOX (VYC*VXC*VZC)

typedef float f4 __attribute__((ext_vector_type(4)));
typedef short s8v __attribute__((ext_vector_type(8)));

__device__ __forceinline__ unsigned short f2bf(float f) {
  union { float f; unsigned u; } v; v.f = f;
  unsigned r = v.u + 0x7FFFu + ((v.u >> 16) & 1u);
  return (unsigned short)(r >> 16);
}
__device__ __forceinline__ float bf2f(unsigned short u) {
  union { unsigned u; float f; } v; v.u = ((unsigned)u) << 16; return v.f;
}

__device__ __forceinline__ bool mask_at(const unsigned char* m, int fl, int idx) {
  if (fl) return m[idx] != 0;
  return ((const int*)m)[idx] != 0;
}

// ---------------- mask detect + per-(b,q) stats ----------------
__global__ __launch_bounds__(1024) void mask_k(const unsigned char* __restrict__ m,
                                               int* __restrict__ flag,
                                               float* __restrict__ invden, float* __restrict__ imc,
                                               float* __restrict__ many) {
  __shared__ int f;
  if (threadIdx.x == 0) f = 0;
  __syncthreads();
  const int total = BB * NCAM * QQ;
  int loc = 0;
  for (int i = threadIdx.x; i < total; i += 1024)
    if ((i & 3) && m[i]) loc = 1;
  if (loc) atomicOr(&f, 1);
  __syncthreads();
  int fl = f;
  if (threadIdx.x == 0) *flag = fl;
  for (int i = threadIdx.x; i < BQ; i += 1024) {
    int b = i / QQ, q = i % QQ;
    float cnt = 0.f;
    for (int n = 0; n < NCAM; ++n)
      cnt += mask_at(m, fl, (b * NCAM + n) * QQ + q) ? 1.f : 0.f;
    float inv = 1.f / (cnt + 1e-6f);
    invden[i] = inv;
    imc[i] = cnt * inv;
    many[i] = cnt > 0.f ? 1.f : 0.f;
  }
}

// ---------------- image transpose [BN,C,H,W] f32 -> [BN,H,W,C] bf16 ----------------
__global__ __launch_bounds__(256) void transpose_img_k(const float* __restrict__ in,
                                                       unsigned short* __restrict__ out) {
  __shared__ float til[32][65];
  int bn = blockIdx.z;
  int c0 = blockIdx.y * 32;
  int yx0 = blockIdx.x * 64;
  int t = threadIdx.x;
  {
    int yx_l = t & 63, c_l = t >> 6;
    int yx = yx0 + yx_l;
#pragma unroll
    for (int i = 0; i < 8; ++i) {
      int c = c_l + 4 * i;
      float v = 0.f;
      if (yx < HWI) v = in[((size_t)(bn * D_MODELC + c0 + c)) * HWI + yx];
      til[c][yx_l] = v;
    }
  }
  __syncthreads();
  {
    int yx_l = t >> 2, cc = (t & 3) * 8;
    int yx = yx0 + yx_l;
    if (yx < HWI) {
      union { unsigned short u[8]; s8v v; } pk;
#pragma unroll
      for (int j = 0; j < 8; ++j) pk.u[j] = f2bf(til[cc + j][yx_l]);
      *(s8v*)(out + ((size_t)bn * HWI + yx) * D_MODELC + c0 + cc) = pk.v;
    }
  }
}

// ---------------- vol zero + winner init ----------------
__global__ __launch_bounds__(256) void zero_vol_k(unsigned short* __restrict__ vol,
                                                  int* __restrict__ winner) {
  int idx = blockIdx.x * 256 + threadIdx.x;
  const int nv16 = (BB * NVOX * 128) / 8;
  if (idx < nv16) {
    uint4 z = make_uint4(0, 0, 0, 0);
    *(uint4*)(vol + (size_t)idx * 8) = z;
  }
  const int nw4 = (BB * NVOX) / 4;
  if (idx < nw4) {
    int4 m = make_int4(-1, -1, -1, -1);
    *(int4*)(winner + (size_t)idx * 4) = m;
  }
}

__global__ void scatter_winner_k(const int* __restrict__ xi, const int* __restrict__ yi,
                                 const int* __restrict__ zi, int* __restrict__ winner) {
  int i = blockIdx.x * blockDim.x + threadIdx.x;
  if (i >= BQ) return;
  int b = i / QQ;
  int vox = yi[i] * (VXC * VZC) + xi[i] * VZC + zi[i];
  atomicMax(&winner[b * NVOX + vox], i % QQ);
}

__global__ void scatter_write_k(const int* __restrict__ xi, const int* __restrict__ yi,
                                const int* __restrict__ zi, const int* __restrict__ winner,
                                const float* __restrict__ qb, unsigned short* __restrict__ vol) {
  int idx = blockIdx.x * blockDim.x + threadIdx.x;
  if (idx >= BQ * 16) return;
  int g = idx & 15, row = idx >> 4;
  int b = row / QQ, q = row % QQ;
  int vox = yi[row] * (VXC * VZC) + xi[row] * VZC + zi[row];
  if (winner[b * NVOX + vox] != q) return;
  const float* src = qb + (size_t)row * 128 + g * 8;
  float4 a = *(const float4*)src;
  float4 c = *(const float4*)(src + 4);
  union { unsigned short u[8]; s8v v; } pk;
  pk.u[0] = f2bf(a.x); pk.u[1] = f2bf(a.y); pk.u[2] = f2bf(a.z); pk.u[3] = f2bf(a.w);
  pk.u[4] = f2bf(c.x); pk.u[5] = f2bf(c.y); pk.u[6] = f2bf(c.z); pk.u[7] = f2bf(c.w);
  *(s8v*)(vol + ((size_t)b * NVOX + vox) * 128 + g * 8) = pk.v;
}

// ---------------- setup: Qbuf = w_w@op_w (z<5) + f1T/f2T bf16 transpose (z>=5) ----------------
__global__ __launch_bounds__(256) void tpre_k(const float* __restrict__ c_w_w, const float* __restrict__ s_w_w,
                                              const float* __restrict__ c_op_w, const float* __restrict__ s_op_w,
                                              const float* __restrict__ cf1, const float* __restrict__ sf1,
                                              const float* __restrict__ cf2, const float* __restrict__ sf2,
                                              float* __restrict__ Qbuf,
                                              unsigned short* __restrict__ f1T, unsigned short* __restrict__ f2T) {
  __shared__ float As_[32][64];
  __shared__ float Ws_[32][64];
  int z = blockIdx.z, tid = threadIdx.x;
  if (z < 5) {
    const float* A = (z < 3) ? c_w_w + (size_t)z * 16384 : s_w_w + (size_t)(z - 3) * 16384;
    const float* Bm = (z < 3) ? c_op_w + (size_t)z * 16384 : s_op_w + (size_t)(z - 3) * 16384;
    float* C = Qbuf + (size_t)z * 16384;
    int m0 = blockIdx.x * 64, n0 = blockIdx.y * 64;
    float acc[4][4] = {};
    int mr = (tid >> 4) * 4, nc = (tid & 15) * 4;
    for (int k0 = 0; k0 < 128; k0 += 32) {
      {
        int r = tid >> 2, kq = (tid & 3) * 8;
        const float* ap = A + (size_t)(m0 + r) * 128 + k0 + kq;
        float4 v0 = *(const float4*)ap, v1 = *(const float4*)(ap + 4);
        As_[kq + 0][r] = v0.x; As_[kq + 1][r] = v0.y; As_[kq + 2][r] = v0.z; As_[kq + 3][r] = v0.w;
        As_[kq + 4][r] = v1.x; As_[kq + 5][r] = v1.y; As_[kq + 6][r] = v1.z; As_[kq + 7][r] = v1.w;
      }
      {
        int kr = tid >> 3, nq = (tid & 7) * 8;
        const float* wp = Bm + (size_t)(k0 + kr) * 128 + n0 + nq;
        *(float4*)&Ws_[kr][nq] = *(const float4*)wp;
        *(float4*)&Ws_[kr][nq + 4] = *(const float4*)(wp + 4);
      }
      __syncthreads();
#pragma unroll
      for (int kk = 0; kk < 32; ++kk) {
        float4 av = *(const float4*)&As_[kk][mr];
        float4 bv = *(const float4*)&Ws_[kk][nc];
        float a_[4] = {av.x, av.y, av.z, av.w};
        float b_[4] = {bv.x, bv.y, bv.z, bv.w};
#pragma unroll
        for (int i = 0; i < 4; ++i)
#pragma unroll
          for (int j = 0; j < 4; ++j) acc[i][j] += a_[i] * b_[j];
      }
      __syncthreads();
    }
#pragma unroll
    for (int i = 0; i < 4; ++i) {
      float4 r;
      r.x = acc[i][0]; r.y = acc[i][1]; r.z = acc[i][2]; r.w = acc[i][3];
      *(float4*)(C + (size_t)(m0 + mr + i) * 128 + n0 + nc) = r;
    }
  } else {
    int bid = (z - 5) * 4 + blockIdx.y * 2 + blockIdx.x;
    int widx = bid >> 6, chunk = bid & 63;
    const float* src; unsigned short* dst; int K, N;
    if (widx < 5) {
      src = (widx < 3) ? cf1 + (size_t)widx * 65536 : sf1 + (size_t)(widx - 3) * 65536;
      dst = f1T + (size_t)widx * 65536; K = 128; N = 512;
    } else {
      int L = widx - 5;
      src = (L < 3) ? cf2 + (size_t)L * 65536 : sf2 + (size_t)(L - 3) * 65536;
      dst = f2T + (size_t)L * 65536; K = 512; N = 128;
    }
    int e = (chunk * 256 + tid) * 4;
    int k = e % K, n = e / K;
    ushort4 o;
    o.x = f2bf(src[(size_t)(k + 0) * N + n]);
    o.y = f2bf(src[(size_t)(k + 1) * N + n]);
    o.z = f2bf(src[(size_t)(k + 2) * N + n]);
    o.w = f2bf(src[(size_t)(k + 3) * N + n]);
    *(ushort4*)(dst + e) = o;
  }
}

// ---------------- setup: Wcbuf = vp_w @ Qbuf ----------------
struct P5 { const float* a[5]; const float* b[5]; float* c[5]; };

__global__ __launch_bounds__(256) void small_mm_k(P5 ps) {
  const float* A = ps.a[blockIdx.z];
  const float* Bm = ps.b[blockIdx.z];
  float* C = ps.c[blockIdx.z];
  __shared__ float As_[32][64];
  __shared__ float Ws_[32][64];
  int m0 = blockIdx.x * 64, n0 = blockIdx.y * 64, tid = threadIdx.x;
  float acc[4][4] = {};
  int mr = (tid >> 4) * 4, nc = (tid & 15) * 4;
  for (int k0 = 0; k0 < 128; k0 += 32) {
    {
      int r = tid >> 2, kq = (tid & 3) * 8;
      const float* ap = A + (size_t)(m0 + r) * 128 + k0 + kq;
      float4 v0 = *(const float4*)ap, v1 = *(const float4*)(ap + 4);
      As_[kq + 0][r] = v0.x; As_[kq + 1][r] = v0.y; As_[kq + 2][r] = v0.z; As_[kq + 3][r] = v0.w;
      As_[kq + 4][r] = v1.x; As_[kq + 5][r] = v1.y; As_[kq + 6][r] = v1.z; As_[kq + 7][r] = v1.w;
    }
    {
      int kr = tid >> 3, nq = (tid & 7) * 8;
      const float* wp = Bm + (size_t)(k0 + kr) * 128 + n0 + nq;
      *(float4*)&Ws_[kr][nq] = *(const float4*)wp;
      *(float4*)&Ws_[kr][nq + 4] = *(const float4*)(wp + 4);
    }
    __syncthreads();
#pragma unroll
    for (int kk = 0; kk < 32; ++kk) {
      float4 av = *(const float4*)&As_[kk][mr];
      float4 bv = *(const float4*)&Ws_[kk][nc];
      float a_[4] = {av.x, av.y, av.z, av.w};
      float b_[4] = {bv.x, bv.y, bv.z, bv.w};
#pragma unroll
      for (int i = 0; i < 4; ++i)
#pragma unroll
        for (int j = 0; j < 4; ++j) acc[i][j] += a_[i] * b_[j];
    }
    __syncthreads();
  }
#pragma unroll
  for (int i = 0; i < 4; ++i) {
    float4 r;
    r.x = acc[i][0]; r.y = acc[i][1]; r.z = acc[i][2]; r.w = acc[i][3];
    *(float4*)(C + (size_t)(m0 + mr + i) * 128 + n0 + nc) = r;
  }
}

// ---------------- setup: WcT conv (y<5) + pre_vec/pjT (y==5) ----------------
__global__ __launch_bounds__(256) void wpre_k(const float* __restrict__ Wcbuf,
                                              unsigned short* __restrict__ WcT,
                                              const float* __restrict__ c_vp_b, const float* __restrict__ c_w_b,
                                              const float* __restrict__ s_vp_b, const float* __restrict__ s_w_b,
                                              const float* __restrict__ c_op_w, const float* __restrict__ s_op_w,
                                              const float* __restrict__ Qbuf,
                                              float* __restrict__ v1buf, float* __restrict__ v2buf,
                                              float* __restrict__ csbuf,
                                              const float* __restrict__ c_dp_w, const float* __restrict__ c_a_w,
                                              const float* __restrict__ s_dp_w, const float* __restrict__ s_a_w,
                                              unsigned short* __restrict__ pjT) {
  int t = threadIdx.x;
  if (blockIdx.y < 5) {
    int L = blockIdx.y;
    const float* src = Wcbuf + (size_t)L * 16384;
    unsigned short* dst = WcT + (size_t)L * 16384;
    int e = (blockIdx.x * 256 + t) * 4;
    int k = e & 127, n = e >> 7;
    ushort4 o;
    o.x = f2bf(src[(size_t)(k + 0) * 128 + n]);
    o.y = f2bf(src[(size_t)(k + 1) * 128 + n]);
    o.z = f2bf(src[(size_t)(k + 2) * 128 + n]);
    o.w = f2bf(src[(size_t)(k + 3) * 128 + n]);
    *(ushort4*)(dst + e) = o;
  } else if (blockIdx.x < 5 && t < 128) {
    int L = blockIdx.x, n = t;
    const float* vpb = L < 3 ? c_vp_b + L * 128 : s_vp_b + (L - 3) * 128;
    const float* wb = L < 3 ? c_w_b + L * 128 : s_w_b + (L - 3) * 128;
    const float* op = L < 3 ? c_op_w + (size_t)L * 16384 : s_op_w + (size_t)(L - 3) * 16384;
    const float* Q = Qbuf + (size_t)L * 16384;
    float a = 0.f, c = 0.f;
    for (int k = 0; k < 128; ++k) {
      a += vpb[k] * Q[k * 128 + n];
      c += wb[k] * op[k * 128 + n];
    }
    if (L < 3) { v1buf[L * 128 + n] = a; v2buf[L * 128 + n] = c; }
    else csbuf[(L - 3) * 128 + n] = a + c;
  } else if (blockIdx.x >= 5 && blockIdx.x < 10) {
    // pjT[L][32 cols][128 k] bf16: proj weights transposed for MFMA B-operand
    int L = blockIdx.x - 5;
    unsigned short* dst = pjT + (size_t)L * 4096;
    for (int e = t * 16; e < t * 16 + 16; ++e) {
      int col = e >> 7, k = e & 127;
      float v = 0.f;
      if (L < 3) {
        if (col < 16) v = c_dp_w[(size_t)L * 2048 + k * 16 + col];
        else if (col < 24) v = c_a_w[(size_t)L * 1024 + k * 8 + (col - 16)];
      } else {
        int i = L - 3;
        if (col < 24) v = s_dp_w[(size_t)i * 3072 + k * 24 + col];
        else v = s_a_w[(size_t)i * 1024 + k * 8 + (col - 24)];
      }
      dst[e] = f2bf(v);
    }
  }
}

// ================= CROSS MEGA: 3 layers fused, 16 rows/block, 1024 thr, 313 blocks =================
__global__ __launch_bounds__(1024) void cross_mega_k(
    const float* __restrict__ query, const float* __restrict__ refp,
    const unsigned char* __restrict__ maskp, const int* __restrict__ flagp,
    const float* __restrict__ invden, const float* __restrict__ imc,
    const unsigned short* __restrict__ imgT,
    const float* __restrict__ ln1g, const float* __restrict__ ln1b,
    const unsigned short* __restrict__ pjT, const float* __restrict__ dpb_,
    const float* __restrict__ ab_,
    const unsigned short* __restrict__ WcT, const float* __restrict__ opb_,
    const float* __restrict__ v1_, const float* __restrict__ v2_,
    const float* __restrict__ ln2g, const float* __restrict__ ln2b,
    const unsigned short* __restrict__ f1T, const float* __restrict__ b1_,
    const unsigned short* __restrict__ f2T, const float* __restrict__ b2_,
    float* __restrict__ qb, int M) {
  __shared__ float qtile[16][132];
  __shared__ float pr[16 * 36];
  __shared__ float awa[16];
  __shared__ __align__(16) unsigned short As[16 * 128];
  __shared__ __align__(16) char scratch[20480];
  int* soff = (int*)scratch;                        // [640][4]
  float* sw = (float*)(scratch + 10240);            // [640][4]
  unsigned short* Hs = (unsigned short*)scratch;    // [16][512]

  int t = threadIdx.x;
  int m0 = blockIdx.x * 16;
  int wv = t >> 6, lane = t & 63;       // 16 waves
  int la = lane & 15, lb = lane >> 4;
  int fl = *flagp;
  int rowW = m0 + wv;                   // this wave's row
  {
    float4 v = make_float4(0, 0, 0, 0);
    if (rowW < M && lane < 32)
      v = *(const float4*)(query + (size_t)rowW * 128 + lane * 4);
    if (lane < 32) *(float4*)&qtile[wv][lane * 4] = v;
  }
  __syncthreads();

  for (int L = 0; L < NCROSS; ++L) {
    const float* dpb = dpb_ + L * 16;
    const float* ab = ab_ + L * 8;
    const float* g1 = ln1g + L * 128;
    const float* be1 = ln1b + L * 128;
    // A1: LN1 (wave per row) -> As bf16 swizzled
    {
      int c0 = lane * 2;
      float x0 = qtile[wv][c0], x1 = qtile[wv][c0 + 1];
      float s1 = x0 + x1, s2 = x0 * x0 + x1 * x1;
#pragma unroll
      for (int msk = 1; msk < 64; msk <<= 1) { s1 += __shfl_xor(s1, msk); s2 += __shfl_xor(s2, msk); }
      float mean = s1 * (1.f / 128.f);
      float var = s2 * (1.f / 128.f) - mean * mean;
      float inv = rsqrtf(var + 1e-5f);
      unsigned u0 = f2bf((x0 - mean) * inv * g1[c0] + be1[c0]);
      unsigned u1 = f2bf((x1 - mean) * inv * g1[c0 + 1] + be1[c0 + 1]);
      int chunk = lane >> 2, idx2 = (lane & 3) * 2;
      *(unsigned*)&As[wv * 128 + ((chunk ^ (wv & 7)) << 3) + idx2] = u0 | (u1 << 16);
    }
    __syncthreads();
    // A2: proj MFMA (waves 0-1): [16x128]@[128x32] -> pr
    if (wv < 2) {
      const unsigned short* pw = pjT + (size_t)L * 4096;
      f4 acc = {};
      int col = wv * 16 + la;
#pragma unroll
      for (int ks = 0; ks < 4; ++ks) {
        s8v af = *(const s8v*)&As[la * 128 + (((ks * 4 + lb) ^ (la & 7)) << 3)];
        s8v bf = *(const s8v*)(pw + (size_t)col * 128 + ks * 32 + lb * 8);
        acc = __builtin_amdgcn_mfma_f32_16x16x32_bf16(af, bf, acc, 0, 0, 0);
      }
#pragma unroll
      for (int j = 0; j < 4; ++j) pr[(lb * 4 + j) * 36 + col] = acc[j];
    }
    __syncthreads();
    // B1: per-entry offsets/weights + inline softmax (640 entries)
    if (t < 640) {
      int qi = t / 40, rem = t % 40;
      int n = rem >> 3, s = rem & 7;
      int row = m0 + qi;
      if (row >= M) {
#pragma unroll
        for (int c = 0; c < 4; ++c) { soff[t * 4 + c] = 0; sw[t * 4 + c] = 0.f; }
      } else {
        int b = row / QQ, q = row - b * QQ;
        int mi = (b * NCAM + n) * QQ + q;
        bool mk = mask_at(maskp, fl, mi);
        float mx = -1e30f;
        float av[8];
#pragma unroll
        for (int i = 0; i < 8; ++i) { av[i] = pr[qi * 36 + 16 + i] + ab[i]; mx = fmaxf(mx, av[i]); }
        float sm = 0.f, es = 0.f;
#pragma unroll
        for (int i = 0; i < 8; ++i) {
          float e_ = expf(av[i] - mx);
          sm += e_;
          if (i == s) es = e_;
        }
        float a = mk ? es / sm : 0.f;
        float rx = refp[(size_t)mi * 2 + 0];
        float ry = refp[(size_t)mi * 2 + 1];
        float fx = (rx + pr[qi * 36 + s * 2 + 0] + dpb[s * 2 + 0]) * (float)(WFI - 1);
        float fy = (ry + pr[qi * 36 + s * 2 + 1] + dpb[s * 2 + 1]) * (float)(HFI - 1);
        float x0f = floorf(fx), y0f = floorf(fy);
        int x0 = (int)x0f, y0 = (int)y0f;
        float xd = fx - x0f, yd = fy - y0f;
        int base = (b * NCAM + n) * HWI;
#pragma unroll
        for (int cy = 0; cy < 2; ++cy)
#pragma unroll
          for (int cx = 0; cx < 2; ++cx) {
            int xi = x0 + cx, yi = y0 + cy;
            bool ok = (xi >= 0) & (xi < WFI) & (yi >= 0) & (yi < HFI);
            int xc = min(max(xi, 0), WFI - 1), yc = min(max(yi, 0), HFI - 1);
            soff[t * 4 + cy * 2 + cx] = (base + yc * WFI + xc) * 128;
            sw[t * 4 + cy * 2 + cx] = ok ? a * (cx ? xd : 1.f - xd) * (cy ? yd : 1.f - yd) : 0.f;
          }
      }
    }
    __syncthreads();
    // B2: gather, wave per query: 4 entry-groups x 16 ch-groups, skip zero entries
    {
      int qi = wv, ln = lane & 15, eg = lane >> 4;
      float acc[8] = {};
      float wa = 0.f;
      for (int e = eg * 10; e < eg * 10 + 10; ++e) {
        int eb = qi * 40 + e;
        float4 wv4 = *(const float4*)&sw[eb * 4];
        float wsum = wv4.x + wv4.y + wv4.z + wv4.w;
        if (wsum != 0.f) {
          int4 ov = *(const int4*)&soff[eb * 4];
          s8v p0 = *(const s8v*)(imgT + (size_t)ov.x + ln * 8);
          s8v p1 = *(const s8v*)(imgT + (size_t)ov.y + ln * 8);
          s8v p2 = *(const s8v*)(imgT + (size_t)ov.z + ln * 8);
          s8v p3 = *(const s8v*)(imgT + (size_t)ov.w + ln * 8);
#pragma unroll
          for (int i = 0; i < 8; ++i)
            acc[i] += wv4.x * bf2f((unsigned short)p0[i]) + wv4.y * bf2f((unsigned short)p1[i])
                    + wv4.z * bf2f((unsigned short)p2[i]) + wv4.w * bf2f((unsigned short)p3[i]);
          wa += wsum;
        }
      }
#pragma unroll
      for (int i = 0; i < 8; ++i) { acc[i] += __shfl_xor(acc[i], 16); acc[i] += __shfl_xor(acc[i], 32); }
      wa += __shfl_xor(wa, 16); wa += __shfl_xor(wa, 32);
      if (eg == 0) {
        union { unsigned short u[8]; s8v v; } pk;
#pragma unroll
        for (int i = 0; i < 8; ++i) pk.u[i] = f2bf(acc[i]);
        *(s8v*)&As[qi * 128 + ((ln ^ (qi & 7)) << 3)] = pk.v;
        if (ln == 0) awa[qi] = wa;
      }
    }
    __syncthreads();
    // B3: op-GEMM + epilogue -> qtile (waves 0-7)
    if (wv < 8) {
      const unsigned short* Wc = WcT + (size_t)L * 16384;
      const float* v1L = v1_ + L * 128;
      const float* v2L = v2_ + L * 128;
      const float* opbL = opb_ + L * 128;
      f4 accm = {};
      int col = wv * 16 + la;
#pragma unroll
      for (int ks = 0; ks < 4; ++ks) {
        s8v af = *(const s8v*)&As[la * 128 + (((ks * 4 + lb) ^ (la & 7)) << 3)];
        s8v bf = *(const s8v*)(Wc + (size_t)col * 128 + ks * 32 + lb * 8);
        accm = __builtin_amdgcn_mfma_f32_16x16x32_bf16(af, bf, accm, 0, 0, 0);
      }
#pragma unroll
      for (int j = 0; j < 4; ++j) {
        int lr = lb * 4 + j;
        int m = m0 + lr;
        float s0m = invden[m];          // safe: ws region, unused rows never stored
        qtile[lr][col] += accm[j] * s0m + s0m * awa[lr] * v1L[col] + imc[m] * v2L[col] + opbL[col];
      }
    }
    __syncthreads();
    // C1: LN2 -> As (wave per row)
    {
      const float* g2 = ln2g + L * 128;
      const float* be2 = ln2b + L * 128;
      int c0 = lane * 2;
      float x0 = qtile[wv][c0], x1 = qtile[wv][c0 + 1];
      float s1 = x0 + x1, s2 = x0 * x0 + x1 * x1;
#pragma unroll
      for (int msk = 1; msk < 64; msk <<= 1) { s1 += __shfl_xor(s1, msk); s2 += __shfl_xor(s2, msk); }
      float mean = s1 * (1.f / 128.f);
      float var = s2 * (1.f / 128.f) - mean * mean;
      float inv = rsqrtf(var + 1e-5f);
      unsigned u0 = f2bf((x0 - mean) * inv * g2[c0] + be2[c0]);
      unsigned u1 = f2bf((x1 - mean) * inv * g2[c0 + 1] + be2[c0 + 1]);
      int chunk = lane >> 2, idx2 = (lane & 3) * 2;
      *(unsigned*)&As[wv * 128 + ((chunk ^ (wv & 7)) << 3) + idx2] = u0 | (u1 << 16);
    }
    __syncthreads();
    // C2: ff1 + GELU -> Hs (16 waves x 2 col-tiles)
    {
      const unsigned short* W1 = f1T + (size_t)L * 65536;
      const float* b1 = b1_ + L * 512;
      f4 acc1[2] = {};
#pragma unroll
      for (int ks = 0; ks < 4; ++ks) {
        s8v af = *(const s8v*)&As[la * 128 + (((ks * 4 + lb) ^ (la & 7)) << 3)];
#pragma unroll
        for (int ti = 0; ti < 2; ++ti) {
          int col = (wv * 2 + ti) * 16 + la;
          s8v bf = *(const s8v*)(W1 + (size_t)col * 128 + ks * 32 + lb * 8);
          acc1[ti] = __builtin_amdgcn_mfma_f32_16x16x32_bf16(af, bf, acc1[ti], 0, 0, 0);
        }
      }
#pragma unroll
      for (int ti = 0; ti < 2; ++ti) {
        int col = (wv * 2 + ti) * 16 + la;
        int chunk = col >> 3, idx = col & 7;
#pragma unroll
        for (int j = 0; j < 4; ++j) {
          int m = lb * 4 + j;
          float val = acc1[ti][j] + b1[col];
          val = 0.5f * val * (1.f + erff(val * 0.70710678118654752f));
          Hs[m * 512 + ((chunk ^ (m & 7)) << 3) + idx] = f2bf(val);
        }
      }
    }
    __syncthreads();
    // C3: ff2 + residual -> qtile (waves 0-7)
    if (wv < 8) {
      const unsigned short* W2 = f2T + (size_t)L * 65536;
      const float* b2 = b2_ + L * 128;
      f4 acc2 = {};
      int col = wv * 16 + la;
#pragma unroll
      for (int ks = 0; ks < 16; ++ks) {
        s8v af = *(const s8v*)&Hs[la * 512 + (((ks * 4 + lb) ^ (la & 7)) << 3)];
        s8v bf = *(const s8v*)(W2 + (size_t)col * 512 + ks * 32 + lb * 8);
        acc2 = __builtin_amdgcn_mfma_f32_16x16x32_bf16(af, bf, acc2, 0, 0, 0);
      }
#pragma unroll
      for (int j = 0; j < 4; ++j) qtile[lb * 4 + j][col] += acc2[j] + b2[col];
    }
    __syncthreads();
  }
  if (rowW < M && lane < 32)
    *(float4*)(qb + (size_t)rowW * 128 + lane * 4) = *(const float4*)&qtile[wv][lane * 4];
}

// ================= SELF MEGA: 1 layer, 16 rows/block, 1024 thr, optional classifier =================
template <bool CLS>
__global__ __launch_bounds__(1024) void self_mega_k(
    const float* __restrict__ qbin, const float* __restrict__ ref3d,
    const unsigned short* __restrict__ vol, const float* __restrict__ many,
    const float* __restrict__ ln1g, const float* __restrict__ ln1b,
    const unsigned short* __restrict__ pjT, const float* __restrict__ dpb,
    const float* __restrict__ ab,
    const unsigned short* __restrict__ WcT, const float* __restrict__ opb,
    const float* __restrict__ csb,
    const float* __restrict__ ln2g, const float* __restrict__ ln2b,
    const unsigned short* __restrict__ f1T, const float* __restrict__ b1,
    const unsigned short* __restrict__ f2T, const float* __restrict__ b2,
    float* __restrict__ qb,
    const float* __restrict__ cw, const float* __restrict__ cb, float* __restrict__ out,
    int M) {
  __shared__ float qtile[16][132];
  __shared__ float pr[16 * 36];
  __shared__ __align__(16) unsigned short As[16 * 128];
  __shared__ __align__(16) char scratch[16896];
  int* soff = (int*)scratch;                      // [128][8]
  float* sw = (float*)(scratch + 4096);           // [128][8]
  unsigned short* Hs = (unsigned short*)scratch;  // [16][512]

  int t = threadIdx.x;
  int m0 = blockIdx.x * 16;
  int wv = t >> 6, lane = t & 63;
  int la = lane & 15, lb = lane >> 4;
  int rowW = m0 + wv;
  {
    float4 v = make_float4(0, 0, 0, 0);
    if (rowW < M && lane < 32)
      v = *(const float4*)(qbin + (size_t)rowW * 128 + lane * 4);
    if (lane < 32) *(float4*)&qtile[wv][lane * 4] = v;
  }
  __syncthreads();
  // A1: LN1 -> As
  {
    int c0 = lane * 2;
    float x0 = qtile[wv][c0], x1 = qtile[wv][c0 + 1];
    float s1 = x0 + x1, s2 = x0 * x0 + x1 * x1;
#pragma unroll
    for (int msk = 1; msk < 64; msk <<= 1) { s1 += __shfl_xor(s1, msk); s2 += __shfl_xor(s2, msk); }
    float mean = s1 * (1.f / 128.f);
    float var = s2 * (1.f / 128.f) - mean * mean;
    float inv = rsqrtf(var + 1e-5f);
    unsigned u0 = f2bf((x0 - mean) * inv * ln1g[c0] + ln1b[c0]);
    unsigned u1 = f2bf((x1 - mean) * inv * ln1g[c0 + 1] + ln1b[c0 + 1]);
    int chunk = lane >> 2, idx2 = (lane & 3) * 2;
    *(unsigned*)&As[wv * 128 + ((chunk ^ (wv & 7)) << 3) + idx2] = u0 | (u1 << 16);
  }
  __syncthreads();
  // A2: proj MFMA (waves 0-1) -> pr[16][32]
  if (wv < 2) {
    f4 acc = {};
    int col = wv * 16 + la;
#pragma unroll
    for (int ks = 0; ks < 4; ++ks) {
      s8v af = *(const s8v*)&As[la * 128 + (((ks * 4 + lb) ^ (la & 7)) << 3)];
      s8v bf = *(const s8v*)(pjT + (size_t)col * 128 + ks * 32 + lb * 8);
      acc = __builtin_amdgcn_mfma_f32_16x16x32_bf16(af, bf, acc, 0, 0, 0);
    }
#pragma unroll
    for (int j = 0; j < 4; ++j) pr[(lb * 4 + j) * 36 + col] = acc[j];
  }
  __syncthreads();
  // B1: per-entry offsets + inline softmax + coords (perm [1,0,2]); 128 entries
  if (t < 128) {
    int qi = t >> 3, s = t & 7;
    int row = m0 + qi;
    if (row >= M) {
#pragma unroll
      for (int c = 0; c < 8; ++c) { soff[t * 8 + c] = 0; sw[t * 8 + c] = 0.f; }
    } else {
      int b = row / QQ;
      float mx = -1e30f;
      float av[8];
#pragma unroll
      for (int i = 0; i < 8; ++i) { av[i] = pr[qi * 36 + 24 + i] + ab[i]; mx = fmaxf(mx, av[i]); }
      float sm = 0.f, es = 0.f;
#pragma unroll
      for (int i = 0; i < 8; ++i) {
        float e_ = expf(av[i] - mx);
        sm += e_;
        if (i == s) es = e_;
      }
      float a = es / sm;
      float g0 = pr[qi * 36 + s * 3 + 1] + dpb[s * 3 + 1] + ref3d[row * 3 + 1];
      float g1v = pr[qi * 36 + s * 3 + 0] + dpb[s * 3 + 0] + ref3d[row * 3 + 0];
      float g2v = pr[qi * 36 + s * 3 + 2] + dpb[s * 3 + 2] + ref3d[row * 3 + 2];
      float fx = (g0 + 1.f) * 0.5f * (float)(VZC - 1);
      float fy = (g1v + 1.f) * 0.5f * (float)(VXC - 1);
      float fz = (g2v + 1.f) * 0.5f * (float)(VYC - 1);
      float x0f = floorf(fx), y0f = floorf(fy), z0f = floorf(fz);
      int x0 = (int)x0f, y0 = (int)y0f, z0 = (int)z0f;
      float xd = fx - x0f, yd = fy - y0f, zd = fz - z0f;
      int base = b * NVOX;
#pragma unroll
      for (int cz = 0; cz < 2; ++cz)
#pragma unroll
        for (int cy = 0; cy < 2; ++cy)
#pragma unroll
          for (int cx = 0; cx < 2; ++cx) {
            int xi = x0 + cx, yi = y0 + cy, zi = z0 + cz;
            bool ok = (xi >= 0) & (xi < VZC) & (yi >= 0) & (yi < VXC) & (zi >= 0) & (zi < VYC);
            int xc = min(max(xi, 0), VZC - 1);
            int yc = min(max(yi, 0), VXC - 1);
            int zc = min(max(zi, 0), VYC - 1);
            int ci = cz * 4 + cy * 2 + cx;
            soff[t * 8 + ci] = (base + (zc * VXC + yc) * VZC + xc) * 128;
            sw[t * 8 + ci] = ok ? a * (cx ? xd : 1.f - xd) * (cy ? yd : 1.f - yd) * (cz ? zd : 1.f - zd) : 0.f;
          }
    }
  }
  __syncthreads();
  // B2: gather, wave per query: 4 entry-groups x 2 samples x 8 corners
  {
    int qi = wv, ln = lane & 15, eg = lane >> 4;
    float acc[8] = {};
#pragma unroll
    for (int ss = 0; ss < 2; ++ss) {
      int eb = qi * 8 + eg * 2 + ss;
#pragma unroll
      for (int c = 0; c < 8; ++c) {
        float wgt = sw[eb * 8 + c];
        if (wgt != 0.f) {
          s8v p = *(const s8v*)(vol + (size_t)soff[eb * 8 + c] + ln * 8);
#pragma unroll
          for (int i = 0; i < 8; ++i) acc[i] += wgt * bf2f((unsigned short)p[i]);
        }
      }
    }
#pragma unroll
    for (int i = 0; i < 8; ++i) { acc[i] += __shfl_xor(acc[i], 16); acc[i] += __shfl_xor(acc[i], 32); }
    if (eg == 0) {
      union { unsigned short u[8]; s8v v; } pk;
#pragma unroll
      for (int i = 0; i < 8; ++i) pk.u[i] = f2bf(acc[i]);
      *(s8v*)&As[qi * 128 + ((ln ^ (qi & 7)) << 3)] = pk.v;
    }
  }
  __syncthreads();
  // B3: op-GEMM + epilogue (waves 0-7)
  if (wv < 8) {
    f4 accm = {};
    int col = wv * 16 + la;
#pragma unroll
    for (int ks = 0; ks < 4; ++ks) {
      s8v af = *(const s8v*)&As[la * 128 + (((ks * 4 + lb) ^ (la & 7)) << 3)];
      s8v bf = *(const s8v*)(WcT + (size_t)col * 128 + ks * 32 + lb * 8);
      accm = __builtin_amdgcn_mfma_f32_16x16x32_bf16(af, bf, accm, 0, 0, 0);
    }
#pragma unroll
    for (int j = 0; j < 4; ++j) {
      int lr = lb * 4 + j;
      int m = m0 + lr;
      float s0m = many[m];
      qtile[lr][col] += accm[j] * s0m + s0m * csb[col] + opb[col];
    }
  }
  __syncthreads();
  // C1: LN2 -> As
  {
    int c0 = lane * 2;
    float x0 = qtile[wv][c0], x1 = qtile[wv][c0 + 1];
    float s1 = x0 + x1, s2 = x0 * x0 + x1 * x1;
#pragma unroll
    for (int msk = 1; msk < 64; msk <<= 1) { s1 += __shfl_xor(s1, msk); s2 += __shfl_xor(s2, msk); }
    float mean = s1 * (1.f / 128.f);
    float var = s2 * (1.f / 128.f) - mean * mean;
    float inv = rsqrtf(var + 1e-5f);
    unsigned u0 = f2bf((x0 - mean) * inv * ln2g[c0] + ln2b[c0]);
    unsigned u1 = f2bf((x1 - mean) * inv * ln2g[c0 + 1] + ln2b[c0 + 1]);
    int chunk = lane >> 2, idx2 = (lane & 3) * 2;
    *(unsigned*)&As[wv * 128 + ((chunk ^ (wv & 7)) << 3) + idx2] = u0 | (u1 << 16);
  }
  __syncthreads();
  // C2: ff1 + GELU -> Hs (16 waves x 2 tiles)
  {
    f4 acc1[2] = {};
#pragma unroll
    for (int ks = 0; ks < 4; ++ks) {
      s8v af = *(const s8v*)&As[la * 128 + (((ks * 4 + lb) ^ (la & 7)) << 3)];
#pragma unroll
      for (int ti = 0; ti < 2; ++ti) {
        int col = (wv * 2 + ti) * 16 + la;
        s8v bf = *(const s8v*)(f1T + (size_t)col * 128 + ks * 32 + lb * 8);
        acc1[ti] = __builtin_amdgcn_mfma_f32_16x16x32_bf16(af, bf, acc1[ti], 0, 0, 0);
      }
    }
#pragma unroll
    for (int ti = 0; ti < 2; ++ti) {
      int col = (wv * 2 + ti) * 16 + la;
      int chunk = col >> 3, idx = col & 7;
#pragma unroll
      for (int j = 0; j < 4; ++j) {
        int m = lb * 4 + j;
        float val = acc1[ti][j] + b1[col];
        val = 0.5f * val * (1.f + erff(val * 0.70710678118654752f));
        Hs[m * 512 + ((chunk ^ (m & 7)) << 3) + idx] = f2bf(val);
      }
    }
  }
  __syncthreads();
  // C3: ff2 + residual (waves 0-7)
  if (wv < 8) {
    f4 acc2 = {};
    int col = wv * 16 + la;
#pragma unroll
    for (int ks = 0; ks < 16; ++ks) {
      s8v af = *(const s8v*)&Hs[la * 512 + (((ks * 4 + lb) ^ (la & 7)) << 3)];
      s8v bf = *(const s8v*)(f2T + (size_t)col * 512 + ks * 32 + lb * 8);
      acc2 = __builtin_amdgcn_mfma_f32_16x16x32_bf16(af, bf, acc2, 0, 0, 0);
    }
#pragma unroll
    for (int j = 0; j < 4; ++j) qtile[lb * 4 + j][col] += acc2[j] + b2[col];
  }
  __syncthreads();
  if (CLS) {
    int c0 = lane * 2;
    float q0 = qtile[wv][c0], q1 = qtile[wv][c0 + 1];
    float ps0 = q0 * cw[c0 * 4 + 0] + q1 * cw[(c0 + 1) * 4 + 0];
    float ps1 = q0 * cw[c0 * 4 + 1] + q1 * cw[(c0 + 1) * 4 + 1];
    float ps2 = q0 * cw[c0 * 4 + 2] + q1 * cw[(c0 + 1) * 4 + 2];
    float ps3 = q0 * cw[c0 * 4 + 3] + q1 * cw[(c0 + 1) * 4 + 3];
#pragma unroll
    for (int msk = 1; msk < 64; msk <<= 1) {
      ps0 += __shfl_xor(ps0, msk);
      ps1 += __shfl_xor(ps1, msk);
      ps2 += __shfl_xor(ps2, msk);
      ps3 += __shfl_xor(ps3, msk);
    }
    if (lane < 4 && rowW < M) {
      float o = (lane == 0) ? ps0 : (lane == 1) ? ps1 : (lane == 2) ? ps2 : ps3;
      out[rowW * 4 + lane] = o + cb[lane];
    }
  } else {
    if (rowW < M && lane < 32)
      *(float4*)(qb + (size_t)rowW * 128 + lane * 4) = *(const float4*)&qtile[wv][lane * 4];
  }
}

extern "C" void kernel_launch(void* const* d_in, const int* in_sizes, int n_in,
                              void* d_out, int out_size, void* d_ws, size_t ws_size,
                              hipStream_t stream) {
  (void)in_sizes; (void)n_in; (void)out_size; (void)ws_size;
  const float* query = (const float*)d_in[0];
  const float* ref_points = (const float*)d_in[1];
  const float* ref3d = (const float*)d_in[2];
  const float* imgf = (const float*)d_in[3];
  const unsigned char* maskp = (const unsigned char*)d_in[4];
  const int* x_idx = (const int*)d_in[5];
  const int* y_idx = (const int*)d_in[6];
  const int* z_idx = (const int*)d_in[7];
  const float* c_ln1_g = (const float*)d_in[8];
  const float* c_ln1_b = (const float*)d_in[9];
  const float* c_dp_w = (const float*)d_in[10];
  const float* c_dp_b = (const float*)d_in[11];
  const float* c_a_w = (const float*)d_in[12];
  const float* c_a_b = (const float*)d_in[13];
  const float* c_w_w = (const float*)d_in[14];
  const float* c_w_b = (const float*)d_in[15];
  const float* c_vp_w = (const float*)d_in[16];
  const float* c_vp_b = (const float*)d_in[17];
  const float* c_op_w = (const float*)d_in[18];
  const float* c_op_b = (const float*)d_in[19];
  const float* c_ln2_g = (const float*)d_in[20];
  const float* c_ln2_b = (const float*)d_in[21];
  const float* c_ff1_w = (const float*)d_in[22];
  const float* c_ff1_b = (const float*)d_in[23];
  const float* c_ff2_w = (const float*)d_in[24];
  const float* c_ff2_b = (const float*)d_in[25];
  const float* s_ln1_g = (const float*)d_in[26];
  const float* s_ln1_b = (const float*)d_in[27];
  const float* s_dp_w = (const float*)d_in[28];
  const float* s_dp_b = (const float*)d_in[29];
  const float* s_a_w = (const float*)d_in[30];
  const float* s_a_b = (const float*)d_in[31];
  const float* s_w_w = (const float*)d_in[32];
  const float* s_w_b = (const float*)d_in[33];
  const float* s_vp_w = (const float*)d_in[34];
  const float* s_vp_b = (const float*)d_in[35];
  const float* s_op_w = (const float*)d_in[36];
  const float* s_op_b = (const float*)d_in[37];
  const float* s_ln2_g = (const float*)d_in[38];
  const float* s_ln2_b = (const float*)d_in[39];
  const float* s_ff1_w = (const float*)d_in[40];
  const float* s_ff1_b = (const float*)d_in[41];
  const float* s_ff2_w = (const float*)d_in[42];
  const float* s_ff2_b = (const float*)d_in[43];
  const float* cls_w = (const float*)d_in[44];
  const float* cls_b = (const float*)d_in[45];
  float* out = (float*)d_out;

  char* ws = (char*)d_ws;
  size_t off = 0;
  auto carve = [&](size_t bytes) -> char* {
    char* p = ws + off;
    off += (bytes + 255) & ~(size_t)255;
    return p;
  };
  int* flag = (int*)carve(256);
  float* invden = (float*)carve(BQ * 4);
  float* imc = (float*)carve(BQ * 4);
  float* many = (float*)carve(BQ * 4);
  float* qb = (float*)carve((size_t)BQ * 128 * 4);
  int* winner = (int*)carve((size_t)BB * NVOX * 4);
  float* Qbuf = (float*)carve((size_t)5 * 16384 * 4);
  float* Wcbuf = (float*)carve((size_t)5 * 16384 * 4);
  unsigned short* WcT = (unsigned short*)carve((size_t)5 * 16384 * 2);
  unsigned short* f1T = (unsigned short*)carve((size_t)5 * 65536 * 2);
  unsigned short* f2T = (unsigned short*)carve((size_t)5 * 65536 * 2);
  unsigned short* pjT = (unsigned short*)carve((size_t)5 * 4096 * 2);
  float* v1buf = (float*)carve(3 * 128 * 4);
  float* v2buf = (float*)carve(3 * 128 * 4);
  float* csbuf = (float*)carve(2 * 128 * 4);
  unsigned short* imgT = (unsigned short*)carve((size_t)BB * NCAM * HWI * 128 * 2);
  unsigned short* vol = (unsigned short*)carve((size_t)BB * NVOX * 128 * 2);

  const int M = BQ;
  const int GB16 = (M + 15) / 16;  // 313

  // ---- setup (7 launches) ----
  mask_k<<<1, 1024, 0, stream>>>(maskp, flag, invden, imc, many);
  tpre_k<<<dim3(2, 2, 165), 256, 0, stream>>>(c_w_w, s_w_w, c_op_w, s_op_w,
                                              c_ff1_w, s_ff1_w, c_ff2_w, s_ff2_w,
                                              Qbuf, f1T, f2T);
  {
    P5 pw;
    for (int L = 0; L < 5; ++L) {
      pw.a[L] = (L < 3) ? c_vp_w + (size_t)L * 16384 : s_vp_w + (size_t)(L - 3) * 16384;
      pw.b[L] = Qbuf + (size_t)L * 16384;
      pw.c[L] = Wcbuf + (size_t)L * 16384;
    }
    small_mm_k<<<dim3(2, 2, 5), 256, 0, stream>>>(pw);
  }
  wpre_k<<<dim3(16, 6), 256, 0, stream>>>(Wcbuf, WcT, c_vp_b, c_w_b, s_vp_b, s_w_b,
                                          c_op_w, s_op_w, Qbuf, v1buf, v2buf, csbuf,
                                          c_dp_w, c_a_w, s_dp_w, s_a_w, pjT);
  transpose_img_k<<<dim3((HWI + 63) / 64, 4, BB * NCAM), 256, 0, stream>>>(imgf, imgT);
  zero_vol_k<<<1024, 256, 0, stream>>>(vol, winner);
  scatter_winner_k<<<(BQ + 255) / 256, 256, 0, stream>>>(x_idx, y_idx, z_idx, winner);

  // ---- cross stack: ONE kernel, 3 layers ----
  cross_mega_k<<<GB16, 1024, 0, stream>>>(query, ref_points, maskp, flag, invden, imc, imgT,
                                          c_ln1_g, c_ln1_b, pjT, c_dp_b, c_a_b,
                                          WcT, c_op_b, v1buf, v2buf, c_ln2_g, c_ln2_b,
                                          f1T, c_ff1_b, f2T, c_ff2_b, qb, M);

  // ---- self stack ----
  scatter_write_k<<<(BQ * 16 + 255) / 256, 256, 0, stream>>>(x_idx, y_idx, z_idx, winner, qb, vol);
  self_mega_k<false><<<GB16, 1024, 0, stream>>>(qb, ref3d, vol, many,
                                                s_ln1_g, s_ln1_b, pjT + (size_t)3 * 4096,
                                                s_dp_b, s_a_b,
                                                WcT + (size_t)3 * 16384, s_op_b, csbuf,
                                                s_ln2_g, s_ln2_b,
                                                f1T + (size_t)3 * 65536, s_ff1_b,
                                                f2T + (size_t)3 * 65536, s_ff2_b,
                                                qb, cls_w, cls_b, out, M);
  scatter_write_k<<<(BQ * 16 + 255) / 256, 256, 0, stream>>>(x_idx, y_idx, z_idx, winner, qb, vol);
  self_mega_k<true><<<GB16, 1024, 0, stream>>>(qb, ref3d, vol, many,
                                               s_ln1_g + 128, s_ln1_b + 128, pjT + (size_t)4 * 4096,
                                               s_dp_b + 24, s_a_b + 8,
                                               WcT + (size_t)4 * 16384, s_op_b + 128,
                                               csbuf + 128, s_ln2_g + 128, s_ln2_b + 128,
                                               f1T + (size_t)4 * 65536, s_ff1_b + 512,
                                               f2T + (size_t)4 * 65536, s_ff2_b + 128,
                                               qb, cls_w, cls_b, out, M);
}